// Round 13
// baseline (145.695 us; speedup 1.0000x reference)
//
#include <hip/hip_runtime.h>
#include <hip/hip_bf16.h>
#include <stdint.h>

#define NN 32768
#define KK 1024
#define DD 256
#define BM 16
#define CHUNK 128
#define NCHUNK (KK / CHUNK)   // 8
#define NTHR 512
#define NRB (NN / BM)         // 2048 row-blocks

// ---- kernel A LDS: Xs 8KB | Ps 64KB (8KB per wave, private) | scratch ----
#define LXS 0
#define LPS 8192
#define ASC_MAXP 73728   // [16 rows][8 waves] {f32 m, i32 mi} = 1024B
#define ASC_ZP   74752   // [16][8] f32 = 512B
#define ASC_MI   75264   // [16] i32
#define LA_TOT   75328

// ---- round-9 fallback LDS ----
#define LSS 8192
#define LRM (LSS + 32768)
#define LRI (LRM + 64)
#define FLPS 41216
#define LTOT_PRE  41216
#define LTOT_NPRE (41216 + 65536)

// ws layout (bytes):
// [0,4096) np2 | [4096,8192) colsum_y | [8192,12288) colsum_lp
// [12288, 536576) pb bf16 protos | [536576, +64MB) Sbuf | then lzbuf f32[NN]
#define PB_OFF   12288
#define SBUF_OFF 536576
#define LZ_OFF   (SBUF_OFF + (size_t)NRB * NCHUNK * 512 * 8)   // 67645440
#define WS_FULL  (LZ_OFF + (size_t)NN * 4)
#define WS_PRE   (PB_OFF + (size_t)KK * DD * 2)

typedef __attribute__((ext_vector_type(8))) short bf16x8;
typedef __attribute__((ext_vector_type(4))) float f32x4;

__device__ __forceinline__ uint32_t pkbf2(float a, float b) {  // RNE f32->bf16 pack
    uint32_t ua = __builtin_bit_cast(uint32_t, a);
    uint32_t ub = __builtin_bit_cast(uint32_t, b);
    ua = (ua + 0x7fffu + ((ua >> 16) & 1u)) >> 16;
    ub = (ub + 0x7fffu + ((ub >> 16) & 1u)) >> 16;
    return ua | (ub << 16);
}
__device__ __forceinline__ float ubf(uint32_t h) {
    return __builtin_bit_cast(float, h << 16);
}

__global__ void vq_init(const float* __restrict__ protos, float* __restrict__ ws) {
    int k = blockIdx.x * 256 + threadIdx.x;   // grid 4 x 256
    const float4* p4 = reinterpret_cast<const float4*>(protos + (size_t)k * DD);
    float s = 0.f;
#pragma unroll 8
    for (int j = 0; j < DD / 4; ++j) {
        float4 v = p4[j];
        s = fmaf(v.x, v.x, s); s = fmaf(v.y, v.y, s);
        s = fmaf(v.z, v.z, s); s = fmaf(v.w, v.w, s);
    }
    ws[k] = s;
    ws[KK + k] = 0.f;
    ws[2 * KK + k] = 0.f;
}

__global__ void vq_cvt(const float* __restrict__ protos, uint32_t* __restrict__ pb) {
    int idx = blockIdx.x * 256 + threadIdx.x;  // 0..32767
    const float4* s = reinterpret_cast<const float4*>(protos + (size_t)idx * 8);
    float4 a = s[0], b = s[1];
    uint4 v;
    v.x = pkbf2(a.x, a.y); v.y = pkbf2(a.z, a.w);
    v.z = pkbf2(b.x, b.y); v.w = pkbf2(b.z, b.w);
    reinterpret_cast<uint4*>(pb)[idx] = v;
}

// ==== kernel A: barrier-free main loop, wave-private Ps slices ====
__global__ __launch_bounds__(NTHR) void vq_mainA(const float* __restrict__ latents,
                                                 const float* __restrict__ protos,
                                                 const float* __restrict__ gumbel,
                                                 float* __restrict__ ws,
                                                 float* __restrict__ out) {
    __shared__ __align__(16) unsigned char sm[LA_TOT];
    const int t = threadIdx.x;
    const int lane = t & 63;
    const int w = t >> 6;
    const int rb = blockIdx.x;
    const int n0 = rb * BM;
    const int l15 = lane & 15;
    const int l4 = lane >> 4;
    const float* np2 = ws;
    const uint4* pb = reinterpret_cast<const uint4*>((char*)ws + PB_OFF);
    uint2* Sb = reinterpret_cast<uint2*>((char*)ws + SBUF_OFF);
    float* lzb = reinterpret_cast<float*>((char*)ws + LZ_OFF);

    // stage X: 16 rows x 256 f32 -> bf16 LDS (swizzled); only block-wide sync
    {
        int row = t >> 5, g = t & 31;
        const float4* src = reinterpret_cast<const float4*>(
            latents + (size_t)(n0 + row) * DD + g * 8);
        float4 a = src[0], b = src[1];
        uint4 v; v.x = pkbf2(a.x, a.y); v.y = pkbf2(a.z, a.w);
        v.z = pkbf2(b.x, b.y); v.w = pkbf2(b.z, b.w);
        *reinterpret_cast<uint4*>(sm + LXS + row * 512 + ((g ^ (row & 7)) << 4)) = v;
    }
    __syncthreads();

    const int wbase = LPS + w * 8192;     // this wave's private Ps slice
    const int cwbase = w * 16 + l4 * 4;
    float z = 0.f, m = -3.4e38f; int mi = 0;

    for (int c = 0; c < NCHUNK; ++c) {
        // ---- wave-private staging: 16 protos x 512B, no block barrier ----
        // In-order per-wave DS ops make write->read->overwrite safe.
#pragma unroll
        for (int i = 0; i < 8; ++i) {
            int G = i * 64 + lane;        // 0..511
            int p = G >> 5;               // local proto 0..15
            int g = G & 31;
            *reinterpret_cast<uint4*>(sm + wbase + p * 512 + ((g ^ (p & 7)) << 4)) =
                pb[(size_t)(c * CHUNK + w * 16 + p) * 32 + g];
        }
        const int pg0 = c * CHUNK + cwbase;
        float4 q4 = *reinterpret_cast<const float4*>(np2 + pg0);
        float4 g4 = *reinterpret_cast<const float4*>(gumbel + (size_t)(n0 + l15) * KK + pg0);

        f32x4 acc = {0.f, 0.f, 0.f, 0.f};
#pragma unroll
        for (int ks = 0; ks < 8; ++ks) {
            int gi = ks * 4 + l4;
            bf16x8 af = *reinterpret_cast<bf16x8*>(
                sm + wbase + l15 * 512 + ((gi ^ (l15 & 7)) << 4));
            bf16x8 b0 = *reinterpret_cast<bf16x8*>(
                sm + LXS + l15 * 512 + ((gi ^ (l15 & 7)) << 4));
            acc = __builtin_amdgcn_mfma_f32_16x16x32_bf16(af, b0, acc, 0, 0, 0);
        }
        float s0 = fmaf(2.f, acc.x, -q4.x) + g4.x;
        float s1 = fmaf(2.f, acc.y, -q4.y) + g4.y;
        float s2 = fmaf(2.f, acc.z, -q4.z) + g4.z;
        float s3 = fmaf(2.f, acc.w, -q4.w) + g4.w;
        z += __expf(s0) + __expf(s1) + __expf(s2) + __expf(s3);
        if (s0 > m) { m = s0; mi = pg0; }
        if (s1 > m) { m = s1; mi = pg0 + 1; }
        if (s2 > m) { m = s2; mi = pg0 + 2; }
        if (s3 > m) { m = s3; mi = pg0 + 3; }
        uint2 pk;
        pk.x = pkbf2(s0, s1);
        pk.y = pkbf2(s2, s3);
        Sb[((size_t)rb * NCHUNK + c) * 512 + t] = pk;   // 512B contiguous per wave
    }

    // row stats: reduce over l4 (lane bits 4,5)
#pragma unroll
    for (int off = 16; off <= 32; off <<= 1) {
        float om = __shfl_xor(m, off); int oi = __shfl_xor(mi, off);
        if (om > m || (om == m && oi < mi)) { m = om; mi = oi; }
        z += __shfl_xor(z, off);
    }
    if (lane < 16) {
        *reinterpret_cast<float*>(sm + ASC_MAXP + (l15 * 8 + w) * 8) = m;
        *reinterpret_cast<int*>(sm + ASC_MAXP + (l15 * 8 + w) * 8 + 4) = mi;
        *reinterpret_cast<float*>(sm + ASC_ZP + (l15 * 8 + w) * 4) = z;
    }
    __syncthreads();
    if (t < 16) {
        float mm = -3.4e38f; int mmi = 0; float Z = 0.f;
#pragma unroll
        for (int j = 0; j < 8; ++j) {
            float om = *reinterpret_cast<float*>(sm + ASC_MAXP + (t * 8 + j) * 8);
            int oi = *reinterpret_cast<int*>(sm + ASC_MAXP + (t * 8 + j) * 8 + 4);
            if (om > mm || (om == mm && oi < mmi)) { mm = om; mmi = oi; }
            Z += *reinterpret_cast<float*>(sm + ASC_ZP + (t * 8 + j) * 4);
        }
        lzb[n0 + t] = __logf(Z);
        *reinterpret_cast<int*>(sm + ASC_MI + t * 4) = mmi;
    }
    __syncthreads();

    // quantized = protos[argmax], 32 thr/row
    {
        int row = t >> 5, v = t & 31;
        int idx = *reinterpret_cast<int*>(sm + ASC_MI + row * 4);
        const float4* src = reinterpret_cast<const float4*>(protos + (size_t)idx * DD + v * 8);
        float4* dst = reinterpret_cast<float4*>(out + (size_t)(n0 + row) * DD + v * 8);
        dst[0] = src[0];
        dst[1] = src[1];
    }
}

// ======= kernel B: column sums from Sbuf =======
__global__ __launch_bounds__(NTHR) void vq_colsum(float* __restrict__ ws) {
    const int t = threadIdx.x;
    const int l15 = t & 15;
    const int c = blockIdx.x & 7;          // chunk
    const int rg = blockIdx.x >> 3;        // row-group: 64 row-blocks
    const uint2* Sb = reinterpret_cast<const uint2*>((char*)ws + SBUF_OFF);
    const float* lzb = reinterpret_cast<const float*>((char*)ws + LZ_OFF);
    float* colsum_y = ws + KK;
    float* colsum_lp = ws + 2 * KK;

    float sy0 = 0.f, sy1 = 0.f, sy2 = 0.f, sy3 = 0.f;
    float sl0 = 0.f, sl1 = 0.f, sl2 = 0.f, sl3 = 0.f;
    for (int i = 0; i < NRB / 32; ++i) {   // 64 row-blocks
        int rb = rg * (NRB / 32) + i;
        uint2 v = Sb[((size_t)rb * NCHUNK + c) * 512 + t];
        float lz = lzb[rb * BM + l15];
        float a0 = ubf(v.x & 0xffffu) - lz, a1 = ubf(v.x >> 16) - lz;
        float a2 = ubf(v.y & 0xffffu) - lz, a3 = ubf(v.y >> 16) - lz;
        sy0 += __expf(a0); sy1 += __expf(a1); sy2 += __expf(a2); sy3 += __expf(a3);
        sl0 += a0; sl1 += a1; sl2 += a2; sl3 += a3;
    }
#pragma unroll
    for (int off = 1; off < 16; off <<= 1) {
        sy0 += __shfl_xor(sy0, off); sy1 += __shfl_xor(sy1, off);
        sy2 += __shfl_xor(sy2, off); sy3 += __shfl_xor(sy3, off);
        sl0 += __shfl_xor(sl0, off); sl1 += __shfl_xor(sl1, off);
        sl2 += __shfl_xor(sl2, off); sl3 += __shfl_xor(sl3, off);
    }
    if (l15 == 0) {
        int w = t >> 6, l4 = (t & 63) >> 4;
        int cb = c * CHUNK + w * 16 + l4 * 4;
        atomicAdd(&colsum_y[cb],     sy0); atomicAdd(&colsum_y[cb + 1], sy1);
        atomicAdd(&colsum_y[cb + 2], sy2); atomicAdd(&colsum_y[cb + 3], sy3);
        atomicAdd(&colsum_lp[cb],     sl0); atomicAdd(&colsum_lp[cb + 1], sl1);
        atomicAdd(&colsum_lp[cb + 2], sl2); atomicAdd(&colsum_lp[cb + 3], sl3);
    }
}

// ======= round-9 fallback main kernel =======
template<bool PRE>
__global__ __launch_bounds__(NTHR) void vq_mainT(const float* __restrict__ latents,
                                                 const float* __restrict__ protos,
                                                 const float* __restrict__ gumbel,
                                                 float* __restrict__ ws,
                                                 float* __restrict__ out) {
    __shared__ __align__(16) unsigned char sm[PRE ? LTOT_PRE : LTOT_NPRE];
    const int t = threadIdx.x;
    const int lane = t & 63;
    const int w = t >> 6;
    const int n0 = blockIdx.x * BM;
    const int l15 = lane & 15;
    const int l4 = lane >> 4;
    const float* np2 = ws;
    float* colsum_y = ws + KK;
    float* colsum_lp = ws + 2 * KK;
    const uint4* pb = reinterpret_cast<const uint4*>((char*)ws + PB_OFF);

    {
        int row = t >> 5, g = t & 31;
        const float4* src = reinterpret_cast<const float4*>(
            latents + (size_t)(n0 + row) * DD + g * 8);
        float4 a = src[0], b = src[1];
        uint4 v; v.x = pkbf2(a.x, a.y); v.y = pkbf2(a.z, a.w);
        v.z = pkbf2(b.x, b.y); v.w = pkbf2(b.z, b.w);
        *reinterpret_cast<uint4*>(sm + LXS + row * 512 + ((g ^ (row & 7)) << 4)) = v;
    }
    __syncthreads();

    const int pr = w * 16 + l15;
    const int cwbase = w * 16 + l4 * 4;

    for (int c = 0; c < NCHUNK; ++c) {
        if (!PRE) {
            __syncthreads();
#pragma unroll
            for (int i = 0; i < 8; ++i) {
                int G = t + NTHR * i;
                int p = G >> 5, g = G & 31;
                const float4* src = reinterpret_cast<const float4*>(
                    protos + (size_t)(c * CHUNK + p) * DD + g * 8);
                float4 a = src[0], b = src[1];
                uint4 v; v.x = pkbf2(a.x, a.y); v.y = pkbf2(a.z, a.w);
                v.z = pkbf2(b.x, b.y); v.w = pkbf2(b.z, b.w);
                *reinterpret_cast<uint4*>(sm + FLPS + p * 512 + ((g ^ (p & 7)) << 4)) = v;
            }
            __syncthreads();
        }
        const int pg0 = c * CHUNK + cwbase;
        float4 q4 = *reinterpret_cast<const float4*>(np2 + pg0);
        float4 g4 = *reinterpret_cast<const float4*>(gumbel + (size_t)(n0 + l15) * KK + pg0);

        f32x4 acc = {0.f, 0.f, 0.f, 0.f};
        if (PRE) {
            const uint4* afp = pb + (size_t)(c * CHUNK + pr) * 32;
#pragma unroll
            for (int ks = 0; ks < 8; ++ks) {
                int gi = ks * 4 + l4;
                bf16x8 af = __builtin_bit_cast(bf16x8, afp[gi]);
                bf16x8 b0 = *reinterpret_cast<bf16x8*>(
                    sm + LXS + l15 * 512 + ((gi ^ (l15 & 7)) << 4));
                acc = __builtin_amdgcn_mfma_f32_16x16x32_bf16(af, b0, acc, 0, 0, 0);
            }
        } else {
#pragma unroll
            for (int ks = 0; ks < 8; ++ks) {
                int gi = ks * 4 + l4;
                bf16x8 af = *reinterpret_cast<bf16x8*>(
                    sm + FLPS + pr * 512 + ((gi ^ (pr & 7)) << 4));
                bf16x8 b0 = *reinterpret_cast<bf16x8*>(
                    sm + LXS + l15 * 512 + ((gi ^ (l15 & 7)) << 4));
                acc = __builtin_amdgcn_mfma_f32_16x16x32_bf16(af, b0, acc, 0, 0, 0);
            }
        }
        {
            const int Gs = pg0 >> 2;
            uint2 pk;
            pk.x = pkbf2(fmaf(2.f, acc.x, -q4.x) + g4.x, fmaf(2.f, acc.y, -q4.y) + g4.y);
            pk.y = pkbf2(fmaf(2.f, acc.z, -q4.z) + g4.z, fmaf(2.f, acc.w, -q4.w) + g4.w);
            *reinterpret_cast<uint2*>(sm + LSS + l15 * 2048 + ((Gs ^ ((l15 & 7) << 1)) << 3)) = pk;
        }
    }
    __syncthreads();

    {
        int row = t >> 5, v = t & 31;
        int sw = (row & 7) << 1;
        uint2 d[8];
#pragma unroll
        for (int j = 0; j < 8; ++j) {
            int G = v + 32 * j;
            d[j] = *reinterpret_cast<uint2*>(sm + LSS + row * 2048 + ((G ^ sw) << 3));
        }
        float m = -3.4e38f; int mi = 0;
#pragma unroll
        for (int j = 0; j < 8; ++j) {
            int c0 = (v + 32 * j) * 4;
            float f0 = ubf(d[j].x & 0xffffu), f1 = ubf(d[j].x >> 16);
            float f2 = ubf(d[j].y & 0xffffu), f3 = ubf(d[j].y >> 16);
            if (f0 > m) { m = f0; mi = c0; }
            if (f1 > m) { m = f1; mi = c0 + 1; }
            if (f2 > m) { m = f2; mi = c0 + 2; }
            if (f3 > m) { m = f3; mi = c0 + 3; }
        }
#pragma unroll
        for (int off = 1; off < 32; off <<= 1) {
            float om = __shfl_xor(m, off);
            int oi = __shfl_xor(mi, off);
            if (om > m || (om == m && oi < mi)) { m = om; mi = oi; }
        }
        float se = 0.f;
#pragma unroll
        for (int j = 0; j < 8; ++j) {
            se += __expf(ubf(d[j].x & 0xffffu) - m);
            se += __expf(ubf(d[j].x >> 16) - m);
            se += __expf(ubf(d[j].y & 0xffffu) - m);
            se += __expf(ubf(d[j].y >> 16) - m);
        }
#pragma unroll
        for (int off = 1; off < 32; off <<= 1) se += __shfl_xor(se, off);
        if (v == 0) {
            *reinterpret_cast<float*>(sm + LRM + row * 4) = m + __logf(se);
            *reinterpret_cast<int*>(sm + LRI + row * 4) = mi;
        }
    }
    __syncthreads();

#pragma unroll
    for (int h = 0; h < 2; ++h) {
        int col = t + h * NTHR;
        int G = col >> 2;
        int e2 = (col & 3) << 1;
        float sy = 0.f, slp = 0.f;
#pragma unroll 8
        for (int r = 0; r < BM; ++r) {
            uint32_t hv = *reinterpret_cast<uint16_t*>(
                sm + LSS + r * 2048 + ((G ^ ((r & 7) << 1)) << 3) + e2);
            float lz = *reinterpret_cast<float*>(sm + LRM + r * 4);
            float lp = ubf(hv) - lz;
            slp += lp;
            sy += __expf(lp);
        }
        atomicAdd(&colsum_y[col], sy);
        atomicAdd(&colsum_lp[col], slp);
    }

    {
        int row = t >> 5, v = t & 31;
        int idx = *reinterpret_cast<int*>(sm + LRI + row * 4);
        const float4* src = reinterpret_cast<const float4*>(protos + (size_t)idx * DD + v * 8);
        float4* dst = reinterpret_cast<float4*>(out + (size_t)(n0 + row) * DD + v * 8);
        dst[0] = src[0];
        dst[1] = src[1];
    }
}

__global__ void vq_final(const float* __restrict__ ws,
                         float* __restrict__ out, int out_size) {
    __shared__ float part[4];
    int t = threadIdx.x;  // 1 block x 256
    const float invN = 1.0f / (float)NN;
    float a = 0.f;
    for (int j = 0; j < 4; ++j) {
        int k = t + j * 256;
        float prior = fmaf(ws[KK + k], invN, 1e-6f);
        float Lk = ws[2 * KK + k] * invN;
        a += prior * (1.001f * __logf(prior) - Lk);
    }
#pragma unroll
    for (int off = 32; off >= 1; off >>= 1) a += __shfl_xor(a, off);
    if ((t & 63) == 0) part[t >> 6] = a;
    __syncthreads();
    if (t == 0) {
        out[out_size - 1] = part[0] + part[1] + part[2] + part[3];
    }
}

extern "C" void kernel_launch(void* const* d_in, const int* in_sizes, int n_in,
                              void* d_out, int out_size, void* d_ws, size_t ws_size,
                              hipStream_t stream) {
    (void)in_sizes; (void)n_in;
    const float* latents = (const float*)d_in[0];
    const float* protos  = (const float*)d_in[1];
    const float* gumbel  = (const float*)d_in[2];
    float* out           = (float*)d_out;
    float* ws            = (float*)d_ws;

    vq_init<<<dim3(4), dim3(256), 0, stream>>>(protos, ws);
    if (ws_size >= WS_FULL) {
        vq_cvt<<<dim3(KK * DD / 2048), dim3(256), 0, stream>>>(
            protos, (uint32_t*)((char*)d_ws + PB_OFF));
        vq_mainA<<<dim3(NRB), dim3(NTHR), 0, stream>>>(
            latents, protos, gumbel, ws, out);
        vq_colsum<<<dim3(NCHUNK * 32), dim3(NTHR), 0, stream>>>(ws);
    } else if (ws_size >= WS_PRE) {
        vq_cvt<<<dim3(KK * DD / 2048), dim3(256), 0, stream>>>(
            protos, (uint32_t*)((char*)d_ws + PB_OFF));
        vq_mainT<true><<<dim3(NRB), dim3(NTHR), 0, stream>>>(
            latents, protos, gumbel, ws, out);
    } else {
        vq_mainT<false><<<dim3(NRB), dim3(NTHR), 0, stream>>>(
            latents, protos, gumbel, ws, out);
    }
    vq_final<<<dim3(1), dim3(256), 0, stream>>>(ws, out, out_size);
}

// Round 14
// 124.792 us; speedup vs baseline: 1.1675x; 1.1675x over previous
//
#include <hip/hip_runtime.h>
#include <hip/hip_bf16.h>
#include <stdint.h>

#define NN 32768
#define KK 1024
#define DD 256
#define BM 32
#define CHUNK 128
#define NCHUNK (KK / CHUNK)   // 8
#define NTHR 512
#define NRB (NN / BM)         // 1024 row-blocks

// ---- kernel A LDS: Ps 64KB (Xs staged in same region pre-loop) + scratch ----
#define A_MAXP 65536     // [32 rows][8 waves] {f32 m, i32 mi} = 2048B
#define A_ZP   67584     // [32][8] f32 = 1024B
#define A_MI   68608     // [32] i32 = 128B
#define LA_TOT 68736

// ---- fallback (round-9 structure, BMF=16) LDS ----
#define BMF 16
#define LXS 0
#define LSS 8192
#define LRM (LSS + 32768)
#define LRI (LRM + 64)
#define FLPS 41216
#define LTOT_PRE  41216
#define LTOT_NPRE (41216 + 65536)

// ws layout (bytes):
// [0,4096) np2 | [4096,8192) colsum_y | [8192,12288) colsum_lp
// [12288, 536576) pb bf16 protos | [536576, +64MB) Sbuf | then lzbuf f32[NN]
#define PB_OFF   12288
#define SBUF_OFF 536576
#define SBUF_BYTES ((size_t)NRB * NCHUNK * 2 * 512 * 8)   // 64MB
#define LZ_OFF   (SBUF_OFF + SBUF_BYTES)
#define WS_FULL  (LZ_OFF + (size_t)NN * 4)
#define WS_PRE   (PB_OFF + (size_t)KK * DD * 2)

typedef __attribute__((ext_vector_type(8))) short bf16x8;
typedef __attribute__((ext_vector_type(4))) float f32x4;

__device__ __forceinline__ uint32_t pkbf2(float a, float b) {  // RNE f32->bf16 pack
    uint32_t ua = __builtin_bit_cast(uint32_t, a);
    uint32_t ub = __builtin_bit_cast(uint32_t, b);
    ua = (ua + 0x7fffu + ((ua >> 16) & 1u)) >> 16;
    ub = (ub + 0x7fffu + ((ub >> 16) & 1u)) >> 16;
    return ua | (ub << 16);
}
__device__ __forceinline__ float ubf(uint32_t h) {
    return __builtin_bit_cast(float, h << 16);
}

__global__ void vq_init(const float* __restrict__ protos, float* __restrict__ ws) {
    int k = blockIdx.x * 256 + threadIdx.x;   // grid 4 x 256
    const float4* p4 = reinterpret_cast<const float4*>(protos + (size_t)k * DD);
    float s = 0.f;
#pragma unroll 8
    for (int j = 0; j < DD / 4; ++j) {
        float4 v = p4[j];
        s = fmaf(v.x, v.x, s); s = fmaf(v.y, v.y, s);
        s = fmaf(v.z, v.z, s); s = fmaf(v.w, v.w, s);
    }
    ws[k] = s;
    ws[KK + k] = 0.f;
    ws[2 * KK + k] = 0.f;
}

__global__ void vq_cvt(const float* __restrict__ protos, uint32_t* __restrict__ pb) {
    int idx = blockIdx.x * 256 + threadIdx.x;  // 0..32767
    const float4* s = reinterpret_cast<const float4*>(protos + (size_t)idx * 8);
    float4 a = s[0], b = s[1];
    uint4 v;
    v.x = pkbf2(a.x, a.y); v.y = pkbf2(a.z, a.w);
    v.z = pkbf2(b.x, b.y); v.w = pkbf2(b.z, b.w);
    reinterpret_cast<uint4*>(pb)[idx] = v;
}

// ==== kernel A: BM=32, X-frags in registers, Ps-only LDS, S -> Sbuf ====
__global__ __launch_bounds__(NTHR) void vq_mainA(const float* __restrict__ latents,
                                                 const float* __restrict__ protos,
                                                 const float* __restrict__ gumbel,
                                                 float* __restrict__ ws,
                                                 float* __restrict__ out) {
    __shared__ __align__(16) unsigned char sm[LA_TOT];
    const int t = threadIdx.x;
    const int lane = t & 63;
    const int w = t >> 6;
    const int rb = blockIdx.x;
    const int n0 = rb * BM;
    const int l15 = lane & 15;
    const int l4 = lane >> 4;
    const float* np2 = ws;
    const uint4* pb = reinterpret_cast<const uint4*>((char*)ws + PB_OFF);
    uint2* Sb = reinterpret_cast<uint2*>((char*)ws + SBUF_OFF);
    float* lzb = reinterpret_cast<float*>((char*)ws + LZ_OFF);

    // ---- prologue: stage X (32 rows x 512B bf16, swizzled) into Ps region ----
    {
        int row = t >> 4;
        int g0 = (t & 15) * 2;
#pragma unroll
        for (int j = 0; j < 2; ++j) {
            int g = g0 + j;
            const float4* src = reinterpret_cast<const float4*>(
                latents + (size_t)(n0 + row) * DD + g * 8);
            float4 a = src[0], b = src[1];
            uint4 v; v.x = pkbf2(a.x, a.y); v.y = pkbf2(a.z, a.w);
            v.z = pkbf2(b.x, b.y); v.w = pkbf2(b.z, b.w);
            *reinterpret_cast<uint4*>(sm + row * 512 + ((g ^ (row & 7)) << 4)) = v;
        }
    }
    __syncthreads();
    // ---- read loop-invariant X fragments into registers (named, static) ----
    const int xsw = l15 & 7;   // same for row l15 and 16+l15
#define LDX(r, k) (*reinterpret_cast<bf16x8*>(sm + (r) * 512 + ((((k) * 4 + l4) ^ xsw) << 4)))
    bf16x8 xa0 = LDX(l15, 0), xa1 = LDX(l15, 1), xa2 = LDX(l15, 2), xa3 = LDX(l15, 3);
    bf16x8 xa4 = LDX(l15, 4), xa5 = LDX(l15, 5), xa6 = LDX(l15, 6), xa7 = LDX(l15, 7);
    bf16x8 xb0 = LDX(16 + l15, 0), xb1 = LDX(16 + l15, 1), xb2 = LDX(16 + l15, 2), xb3 = LDX(16 + l15, 3);
    bf16x8 xb4 = LDX(16 + l15, 4), xb5 = LDX(16 + l15, 5), xb6 = LDX(16 + l15, 6), xb7 = LDX(16 + l15, 7);
#undef LDX

    const int pr = w * 16 + l15;          // proto row within chunk
    const int cwbase = w * 16 + l4 * 4;
    float z0 = 0.f, m0 = -3.4e38f; int mi0 = 0;
    float z1 = 0.f, m1 = -3.4e38f; int mi1 = 0;

    for (int c = 0; c < NCHUNK; ++c) {
        __syncthreads();   // prev chunk reads done (c=0: frag reads done)
        // ---- stage Ps: 128 protos x 512B, cooperative ----
#pragma unroll
        for (int i = 0; i < 8; ++i) {
            int G = t + NTHR * i;
            int p = G >> 5, g = G & 31;
            *reinterpret_cast<uint4*>(sm + p * 512 + ((g ^ (p & 7)) << 4)) =
                pb[(size_t)(c * CHUNK + p) * 32 + g];
        }
        const int pg0 = c * CHUNK + cwbase;
        float4 q4 = *reinterpret_cast<const float4*>(np2 + pg0);
        float4 g40 = *reinterpret_cast<const float4*>(gumbel + (size_t)(n0 + l15) * KK + pg0);
        float4 g41 = *reinterpret_cast<const float4*>(gumbel + (size_t)(n0 + 16 + l15) * KK + pg0);
        __syncthreads();   // Ps visible

        f32x4 acc0 = {0.f, 0.f, 0.f, 0.f}, acc1 = {0.f, 0.f, 0.f, 0.f};
#define KSTEP(k, xa, xb) { \
        bf16x8 af = *reinterpret_cast<bf16x8*>(sm + pr * 512 + ((((k) * 4 + l4) ^ (pr & 7)) << 4)); \
        acc0 = __builtin_amdgcn_mfma_f32_16x16x32_bf16(af, xa, acc0, 0, 0, 0); \
        acc1 = __builtin_amdgcn_mfma_f32_16x16x32_bf16(af, xb, acc1, 0, 0, 0); }
        KSTEP(0, xa0, xb0) KSTEP(1, xa1, xb1) KSTEP(2, xa2, xb2) KSTEP(3, xa3, xb3)
        KSTEP(4, xa4, xb4) KSTEP(5, xa5, xb5) KSTEP(6, xa6, xb6) KSTEP(7, xa7, xb7)
#undef KSTEP

        // ---- epilogue row l15 ----
        float s0 = fmaf(2.f, acc0.x, -q4.x) + g40.x;
        float s1 = fmaf(2.f, acc0.y, -q4.y) + g40.y;
        float s2 = fmaf(2.f, acc0.z, -q4.z) + g40.z;
        float s3 = fmaf(2.f, acc0.w, -q4.w) + g40.w;
        z0 += __expf(s0) + __expf(s1) + __expf(s2) + __expf(s3);
        if (s0 > m0) { m0 = s0; mi0 = pg0; }
        if (s1 > m0) { m0 = s1; mi0 = pg0 + 1; }
        if (s2 > m0) { m0 = s2; mi0 = pg0 + 2; }
        if (s3 > m0) { m0 = s3; mi0 = pg0 + 3; }
        uint2 pk0; pk0.x = pkbf2(s0, s1); pk0.y = pkbf2(s2, s3);
        Sb[(((size_t)rb * NCHUNK + c) * 2 + 0) * 512 + t] = pk0;
        // ---- epilogue row 16+l15 ----
        float u0 = fmaf(2.f, acc1.x, -q4.x) + g41.x;
        float u1 = fmaf(2.f, acc1.y, -q4.y) + g41.y;
        float u2 = fmaf(2.f, acc1.z, -q4.z) + g41.z;
        float u3 = fmaf(2.f, acc1.w, -q4.w) + g41.w;
        z1 += __expf(u0) + __expf(u1) + __expf(u2) + __expf(u3);
        if (u0 > m1) { m1 = u0; mi1 = pg0; }
        if (u1 > m1) { m1 = u1; mi1 = pg0 + 1; }
        if (u2 > m1) { m1 = u2; mi1 = pg0 + 2; }
        if (u3 > m1) { m1 = u3; mi1 = pg0 + 3; }
        uint2 pk1; pk1.x = pkbf2(u0, u1); pk1.y = pkbf2(u2, u3);
        Sb[(((size_t)rb * NCHUNK + c) * 2 + 1) * 512 + t] = pk1;
    }

    // ---- row stats: reduce over l4 (lane bits 4,5), then across waves ----
#pragma unroll
    for (int off = 16; off <= 32; off <<= 1) {
        float om = __shfl_xor(m0, off); int oi = __shfl_xor(mi0, off);
        if (om > m0 || (om == m0 && oi < mi0)) { m0 = om; mi0 = oi; }
        om = __shfl_xor(m1, off); oi = __shfl_xor(mi1, off);
        if (om > m1 || (om == m1 && oi < mi1)) { m1 = om; mi1 = oi; }
        z0 += __shfl_xor(z0, off);
        z1 += __shfl_xor(z1, off);
    }
    __syncthreads();   // Ps reads finished; scratch region safe (it's past 64KB anyway)
    if (lane < 16) {
        *reinterpret_cast<float*>(sm + A_MAXP + (l15 * 8 + w) * 8) = m0;
        *reinterpret_cast<int*>(sm + A_MAXP + (l15 * 8 + w) * 8 + 4) = mi0;
        *reinterpret_cast<float*>(sm + A_MAXP + ((16 + l15) * 8 + w) * 8) = m1;
        *reinterpret_cast<int*>(sm + A_MAXP + ((16 + l15) * 8 + w) * 8 + 4) = mi1;
        *reinterpret_cast<float*>(sm + A_ZP + (l15 * 8 + w) * 4) = z0;
        *reinterpret_cast<float*>(sm + A_ZP + ((16 + l15) * 8 + w) * 4) = z1;
    }
    __syncthreads();
    if (t < 32) {
        float mm = -3.4e38f; int mmi = 0; float Z = 0.f;
#pragma unroll
        for (int j = 0; j < 8; ++j) {
            float om = *reinterpret_cast<float*>(sm + A_MAXP + (t * 8 + j) * 8);
            int oi = *reinterpret_cast<int*>(sm + A_MAXP + (t * 8 + j) * 8 + 4);
            if (om > mm || (om == mm && oi < mmi)) { mm = om; mmi = oi; }
            Z += *reinterpret_cast<float*>(sm + A_ZP + (t * 8 + j) * 4);
        }
        lzb[n0 + t] = __logf(Z);
        *reinterpret_cast<int*>(sm + A_MI + t * 4) = mmi;
    }
    __syncthreads();

    // ---- quantized = protos[argmax], 16 thr/row x 64B ----
    {
        int row = t >> 4, v = t & 15;
        int idx = *reinterpret_cast<int*>(sm + A_MI + row * 4);
        const float4* src = reinterpret_cast<const float4*>(protos + (size_t)idx * DD + v * 16);
        float4* dst = reinterpret_cast<float4*>(out + (size_t)(n0 + row) * DD + v * 16);
#pragma unroll
        for (int j = 0; j < 4; ++j) dst[j] = src[j];
    }
}

// ======= kernel B: column sums from Sbuf =======
__global__ __launch_bounds__(NTHR) void vq_colsum(float* __restrict__ ws) {
    const int t = threadIdx.x;
    const int l15 = t & 15;
    const int c = blockIdx.x & 7;          // chunk
    const int rg = blockIdx.x >> 3;        // row-group 0..31 (32 rbs each)
    const uint2* Sb = reinterpret_cast<const uint2*>((char*)ws + SBUF_OFF);
    const float* lzb = reinterpret_cast<const float*>((char*)ws + LZ_OFF);
    float* colsum_y = ws + KK;
    float* colsum_lp = ws + 2 * KK;

    float sy0 = 0.f, sy1 = 0.f, sy2 = 0.f, sy3 = 0.f;
    float sl0 = 0.f, sl1 = 0.f, sl2 = 0.f, sl3 = 0.f;
    for (int i = 0; i < NRB / 32; ++i) {   // 32 row-blocks
        int rb = rg * (NRB / 32) + i;
#pragma unroll
        for (int h = 0; h < 2; ++h) {
            uint2 v = Sb[(((size_t)rb * NCHUNK + c) * 2 + h) * 512 + t];
            float lz = lzb[rb * BM + h * 16 + l15];
            float a0 = ubf(v.x & 0xffffu) - lz, a1 = ubf(v.x >> 16) - lz;
            float a2 = ubf(v.y & 0xffffu) - lz, a3 = ubf(v.y >> 16) - lz;
            sy0 += __expf(a0); sy1 += __expf(a1); sy2 += __expf(a2); sy3 += __expf(a3);
            sl0 += a0; sl1 += a1; sl2 += a2; sl3 += a3;
        }
    }
#pragma unroll
    for (int off = 1; off < 16; off <<= 1) {
        sy0 += __shfl_xor(sy0, off); sy1 += __shfl_xor(sy1, off);
        sy2 += __shfl_xor(sy2, off); sy3 += __shfl_xor(sy3, off);
        sl0 += __shfl_xor(sl0, off); sl1 += __shfl_xor(sl1, off);
        sl2 += __shfl_xor(sl2, off); sl3 += __shfl_xor(sl3, off);
    }
    if (l15 == 0) {
        int w = t >> 6, l4 = (t & 63) >> 4;
        int cb = c * CHUNK + w * 16 + l4 * 4;
        atomicAdd(&colsum_y[cb],     sy0); atomicAdd(&colsum_y[cb + 1], sy1);
        atomicAdd(&colsum_y[cb + 2], sy2); atomicAdd(&colsum_y[cb + 3], sy3);
        atomicAdd(&colsum_lp[cb],     sl0); atomicAdd(&colsum_lp[cb + 1], sl1);
        atomicAdd(&colsum_lp[cb + 2], sl2); atomicAdd(&colsum_lp[cb + 3], sl3);
    }
}

// ======= fallback main kernel (round-9 structure, BMF=16) =======
template<bool PRE>
__global__ __launch_bounds__(NTHR) void vq_mainT(const float* __restrict__ latents,
                                                 const float* __restrict__ protos,
                                                 const float* __restrict__ gumbel,
                                                 float* __restrict__ ws,
                                                 float* __restrict__ out) {
    __shared__ __align__(16) unsigned char sm[PRE ? LTOT_PRE : LTOT_NPRE];
    const int t = threadIdx.x;
    const int lane = t & 63;
    const int w = t >> 6;
    const int n0 = blockIdx.x * BMF;
    const int l15 = lane & 15;
    const int l4 = lane >> 4;
    const float* np2 = ws;
    float* colsum_y = ws + KK;
    float* colsum_lp = ws + 2 * KK;
    const uint4* pb = reinterpret_cast<const uint4*>((char*)ws + PB_OFF);

    {
        int row = t >> 5, g = t & 31;
        const float4* src = reinterpret_cast<const float4*>(
            latents + (size_t)(n0 + row) * DD + g * 8);
        float4 a = src[0], b = src[1];
        uint4 v; v.x = pkbf2(a.x, a.y); v.y = pkbf2(a.z, a.w);
        v.z = pkbf2(b.x, b.y); v.w = pkbf2(b.z, b.w);
        *reinterpret_cast<uint4*>(sm + LXS + row * 512 + ((g ^ (row & 7)) << 4)) = v;
    }
    __syncthreads();

    const int pr = w * 16 + l15;
    const int cwbase = w * 16 + l4 * 4;

    for (int c = 0; c < 8; ++c) {
        if (!PRE) {
            __syncthreads();
#pragma unroll
            for (int i = 0; i < 8; ++i) {
                int G = t + NTHR * i;
                int p = G >> 5, g = G & 31;
                const float4* src = reinterpret_cast<const float4*>(
                    protos + (size_t)(c * 128 + p) * DD + g * 8);
                float4 a = src[0], b = src[1];
                uint4 v; v.x = pkbf2(a.x, a.y); v.y = pkbf2(a.z, a.w);
                v.z = pkbf2(b.x, b.y); v.w = pkbf2(b.z, b.w);
                *reinterpret_cast<uint4*>(sm + FLPS + p * 512 + ((g ^ (p & 7)) << 4)) = v;
            }
            __syncthreads();
        }
        const int pg0 = c * 128 + cwbase;
        float4 q4 = *reinterpret_cast<const float4*>(np2 + pg0);
        float4 g4 = *reinterpret_cast<const float4*>(gumbel + (size_t)(n0 + l15) * KK + pg0);

        f32x4 acc = {0.f, 0.f, 0.f, 0.f};
        if (PRE) {
            const uint4* afp = pb + (size_t)(c * 128 + pr) * 32;
#pragma unroll
            for (int ks = 0; ks < 8; ++ks) {
                int gi = ks * 4 + l4;
                bf16x8 af = __builtin_bit_cast(bf16x8, afp[gi]);
                bf16x8 b0 = *reinterpret_cast<bf16x8*>(
                    sm + LXS + l15 * 512 + ((gi ^ (l15 & 7)) << 4));
                acc = __builtin_amdgcn_mfma_f32_16x16x32_bf16(af, b0, acc, 0, 0, 0);
            }
        } else {
#pragma unroll
            for (int ks = 0; ks < 8; ++ks) {
                int gi = ks * 4 + l4;
                bf16x8 af = *reinterpret_cast<bf16x8*>(
                    sm + FLPS + pr * 512 + ((gi ^ (pr & 7)) << 4));
                bf16x8 b0 = *reinterpret_cast<bf16x8*>(
                    sm + LXS + l15 * 512 + ((gi ^ (l15 & 7)) << 4));
                acc = __builtin_amdgcn_mfma_f32_16x16x32_bf16(af, b0, acc, 0, 0, 0);
            }
        }
        {
            const int Gs = pg0 >> 2;
            uint2 pk;
            pk.x = pkbf2(fmaf(2.f, acc.x, -q4.x) + g4.x, fmaf(2.f, acc.y, -q4.y) + g4.y);
            pk.y = pkbf2(fmaf(2.f, acc.z, -q4.z) + g4.z, fmaf(2.f, acc.w, -q4.w) + g4.w);
            *reinterpret_cast<uint2*>(sm + LSS + l15 * 2048 + ((Gs ^ ((l15 & 7) << 1)) << 3)) = pk;
        }
    }
    __syncthreads();

    {
        int row = t >> 5, v = t & 31;
        int sw = (row & 7) << 1;
        uint2 d[8];
#pragma unroll
        for (int j = 0; j < 8; ++j) {
            int G = v + 32 * j;
            d[j] = *reinterpret_cast<uint2*>(sm + LSS + row * 2048 + ((G ^ sw) << 3));
        }
        float m = -3.4e38f; int mi = 0;
#pragma unroll
        for (int j = 0; j < 8; ++j) {
            int c0 = (v + 32 * j) * 4;
            float f0 = ubf(d[j].x & 0xffffu), f1 = ubf(d[j].x >> 16);
            float f2 = ubf(d[j].y & 0xffffu), f3 = ubf(d[j].y >> 16);
            if (f0 > m) { m = f0; mi = c0; }
            if (f1 > m) { m = f1; mi = c0 + 1; }
            if (f2 > m) { m = f2; mi = c0 + 2; }
            if (f3 > m) { m = f3; mi = c0 + 3; }
        }
#pragma unroll
        for (int off = 1; off < 32; off <<= 1) {
            float om = __shfl_xor(m, off);
            int oi = __shfl_xor(mi, off);
            if (om > m || (om == m && oi < mi)) { m = om; mi = oi; }
        }
        float se = 0.f;
#pragma unroll
        for (int j = 0; j < 8; ++j) {
            se += __expf(ubf(d[j].x & 0xffffu) - m);
            se += __expf(ubf(d[j].x >> 16) - m);
            se += __expf(ubf(d[j].y & 0xffffu) - m);
            se += __expf(ubf(d[j].y >> 16) - m);
        }
#pragma unroll
        for (int off = 1; off < 32; off <<= 1) se += __shfl_xor(se, off);
        if (v == 0) {
            *reinterpret_cast<float*>(sm + LRM + row * 4) = m + __logf(se);
            *reinterpret_cast<int*>(sm + LRI + row * 4) = mi;
        }
    }
    __syncthreads();

#pragma unroll
    for (int h = 0; h < 2; ++h) {
        int col = t + h * NTHR;
        int G = col >> 2;
        int e2 = (col & 3) << 1;
        float sy = 0.f, slp = 0.f;
#pragma unroll 8
        for (int r = 0; r < BMF; ++r) {
            uint32_t hv = *reinterpret_cast<uint16_t*>(
                sm + LSS + r * 2048 + ((G ^ ((r & 7) << 1)) << 3) + e2);
            float lz = *reinterpret_cast<float*>(sm + LRM + r * 4);
            float lp = ubf(hv) - lz;
            slp += lp;
            sy += __expf(lp);
        }
        atomicAdd(&colsum_y[col], sy);
        atomicAdd(&colsum_lp[col], slp);
    }

    {
        int row = t >> 5, v = t & 31;
        int idx = *reinterpret_cast<int*>(sm + LRI + row * 4);
        const float4* src = reinterpret_cast<const float4*>(protos + (size_t)idx * DD + v * 8);
        float4* dst = reinterpret_cast<float4*>(out + (size_t)(n0 + row) * DD + v * 8);
        dst[0] = src[0];
        dst[1] = src[1];
    }
}

__global__ void vq_final(const float* __restrict__ ws,
                         float* __restrict__ out, int out_size) {
    __shared__ float part[4];
    int t = threadIdx.x;  // 1 block x 256
    const float invN = 1.0f / (float)NN;
    float a = 0.f;
    for (int j = 0; j < 4; ++j) {
        int k = t + j * 256;
        float prior = fmaf(ws[KK + k], invN, 1e-6f);
        float Lk = ws[2 * KK + k] * invN;
        a += prior * (1.001f * __logf(prior) - Lk);
    }
#pragma unroll
    for (int off = 32; off >= 1; off >>= 1) a += __shfl_xor(a, off);
    if ((t & 63) == 0) part[t >> 6] = a;
    __syncthreads();
    if (t == 0) {
        out[out_size - 1] = part[0] + part[1] + part[2] + part[3];
    }
}

extern "C" void kernel_launch(void* const* d_in, const int* in_sizes, int n_in,
                              void* d_out, int out_size, void* d_ws, size_t ws_size,
                              hipStream_t stream) {
    (void)in_sizes; (void)n_in;
    const float* latents = (const float*)d_in[0];
    const float* protos  = (const float*)d_in[1];
    const float* gumbel  = (const float*)d_in[2];
    float* out           = (float*)d_out;
    float* ws            = (float*)d_ws;

    vq_init<<<dim3(4), dim3(256), 0, stream>>>(protos, ws);
    if (ws_size >= WS_FULL) {
        vq_cvt<<<dim3(KK * DD / 2048), dim3(256), 0, stream>>>(
            protos, (uint32_t*)((char*)d_ws + PB_OFF));
        vq_mainA<<<dim3(NRB), dim3(NTHR), 0, stream>>>(
            latents, protos, gumbel, ws, out);
        vq_colsum<<<dim3(NCHUNK * 32), dim3(NTHR), 0, stream>>>(ws);
    } else if (ws_size >= WS_PRE) {
        vq_cvt<<<dim3(KK * DD / 2048), dim3(256), 0, stream>>>(
            protos, (uint32_t*)((char*)d_ws + PB_OFF));
        vq_mainT<true><<<dim3(NN / BMF), dim3(NTHR), 0, stream>>>(
            latents, protos, gumbel, ws, out);
    } else {
        vq_mainT<false><<<dim3(NN / BMF), dim3(NTHR), 0, stream>>>(
            latents, protos, gumbel, ws, out);
    }
    vq_final<<<dim3(1), dim3(256), 0, stream>>>(ws, out, out_size);
}